// Round 4
// baseline (28.518 us; speedup 1.0000x reference)
//
#include <hip/hip_runtime.h>

// out[b,f] = x[b,f] * S. Algebraic collapse of the reference:
//   x real, per-channel factors are complex scalars, crosstalk M is real,
//   real() is taken before the softmax-weighted channel sum, so
//   Re(factor_c) = gain_c * cos(phase_c + 0.5*D*(wl_c - mean(wl))^2) * sigmoid(aw_c)
//   S = sum_k softmax(aw)[k] * sum_c Re(factor_c) * M[c,k]
//
// Accuracy note: the dispersion phases are ~1e5; fast-math cosf (native
// v_cos_f32) loses ~9 fractional bits in its f32 revolutions-scaling and
// produced 2.7e-2 absmax (R2 failure). Fix: range reduction in DOUBLE
// ARITHMETIC ONLY (mul/rint/fma, no double transcendentals, ~20 f64 VALU
// ops), then cosf on the small reduced argument. Every thread computes S
// redundantly -> no barrier, no LDS, no serialized prologue.
//
// nontemporal builtins need a native clang vector type, not HIP's
// float4 class (R3 compile failure) -> use ext_vector_type(4).

typedef float f32x4 __attribute__((ext_vector_type(4)));

__global__ __launch_bounds__(256) void wdm_scale_kernel(
    const float* __restrict__ x,
    const float* __restrict__ gains,
    const float* __restrict__ phases,
    const float* __restrict__ aw,
    const float* __restrict__ disp,
    const float* __restrict__ ct,     // [3][3] row-major, M[c][k]
    const float* __restrict__ wl,
    float* __restrict__ out,
    long n4)                           // number of float4 elements
{
    // ---- scalar S, all-thread redundant, f64 only for phase reduction ----
    const double TWO_PI     = 6.283185307179586;
    const double INV_TWO_PI = 0.15915494309189535;

    const float w0 = wl[0], w1 = wl[1], w2 = wl[2];
    const float wlm = (w0 + w1 + w2) * (1.0f / 3.0f);
    const double D = (double)disp[0];

    const float a0 = aw[0], a1 = aw[1], a2 = aw[2];
    const float awm = fmaxf(fmaxf(a0, a1), a2);
    const float wls[3] = {w0, w1, w2};
    const float as[3]  = {a0, a1, a2};

    float re[3], ex[3];
    float sumex = 0.0f;
    #pragma unroll
    for (int c = 0; c < 3; ++c) {
        double d  = (double)wls[c] - (double)wlm;
        double ph = (double)phases[c] + 0.5 * D * d * d;
        // reduce ph mod 2*pi to [-pi, pi] in double (exact to ~4e-12 rad)
        double k = __builtin_rint(ph * INV_TWO_PI);
        float r  = (float)(ph - k * TWO_PI);
        float sg = 1.0f / (1.0f + expf(-as[c]));
        re[c] = gains[c] * cosf(r) * sg;
        ex[c] = expf(as[c] - awm);
        sumex += ex[c];
    }
    float S = 0.0f;
    #pragma unroll
    for (int k = 0; k < 3; ++k) {
        float acc = 0.0f;
        #pragma unroll
        for (int c = 0; c < 3; ++c) acc += re[c] * ct[c * 3 + k];
        S += (ex[k] / sumex) * acc;
    }

    // ---- streaming scale: whole-16B nontemporal load/store ----
    const f32x4* __restrict__ x4 = (const f32x4*)x;
    f32x4* __restrict__ o4 = (f32x4*)out;

    long i = (long)blockIdx.x * blockDim.x + threadIdx.x;
    const long stride = (long)gridDim.x * blockDim.x;
    for (; i < n4; i += stride) {
        f32x4 v = __builtin_nontemporal_load(&x4[i]);
        v *= S;
        __builtin_nontemporal_store(v, &o4[i]);
    }
}

extern "C" void kernel_launch(void* const* d_in, const int* in_sizes, int n_in,
                              void* d_out, int out_size, void* d_ws, size_t ws_size,
                              hipStream_t stream) {
    const float* x      = (const float*)d_in[0];
    const float* gains  = (const float*)d_in[1];
    const float* phases = (const float*)d_in[2];
    const float* aw     = (const float*)d_in[3];
    const float* disp   = (const float*)d_in[4];
    const float* ct     = (const float*)d_in[5];
    const float* wl     = (const float*)d_in[6];
    float* out = (float*)d_out;

    long n = (long)in_sizes[0];          // 4096*4096, divisible by 4
    long n4 = n >> 2;

    int block = 256;
    long want = (n4 + block - 1) / block;
    int grid = (int)(want < 2048 ? want : 2048);

    wdm_scale_kernel<<<grid, block, 0, stream>>>(x, gains, phases, aw, disp,
                                                 ct, wl, out, n4);
}